// Round 2
// baseline (712.431 us; speedup 1.0000x reference)
//
#include <hip/hip_runtime.h>

#define B_ROWS   131072
#define KCHUNKS  17                                   // 544 / 32
// ws layout: mask u32 [0,512K); W1t fp16 [512][544] at W1T_OFF; X1 fp16 [B][544] at X1_OFF
#define W1T_OFF  ((size_t)B_ROWS * 4)
#define X1_OFF   (W1T_OFF + (size_t)512 * 544 * 2)
#define WS_NEED  (X1_OFF + (size_t)B_ROWS * 544 * 2)

typedef _Float16 f16x8 __attribute__((ext_vector_type(8)));
typedef float    f32x4 __attribute__((ext_vector_type(4)));

__device__ inline unsigned short f2h(float f) {
  _Float16 h = (_Float16)f;
  return __builtin_bit_cast(unsigned short, h);
}
__device__ inline float selu_f(float x) {
  const float lam = 1.0507009873554805f, alp = 1.6732632423543772f;
  return x > 0.f ? lam * x : lam * alp * (__expf(x) - 1.f);
}
__device__ inline void gld16(const void* g, void* l) {
  __builtin_amdgcn_global_load_lds(
      (const __attribute__((address_space(1))) unsigned int*)g,
      (__attribute__((address_space(3))) unsigned int*)l, 16, 0, 0);
}

__global__ void scatter_mask(const int* __restrict__ coords,
                             unsigned int* __restrict__ mask) {
  int i = blockIdx.x * 256 + threadIdx.x;
  mask[coords[i]] = 1u;
}

// W1 fp32 [526][512] -> W1t fp16 [n=512][k=544] (K-permuted: features first, jnt at 512..525)
// via coalesced LDS tile transpose.
__global__ __launch_bounds__(256) void build_w1t(const float* __restrict__ W1,
                                                 unsigned short* __restrict__ W1t) {
  __shared__ float tile[32][33];
  const int k0 = blockIdx.x * 32;   // 0..544 in steps of 32 (17 blocks)
  const int n0 = blockIdx.y * 32;   // 0..512 in steps of 32 (16 blocks)
  const int tr = threadIdx.x >> 5;  // 0..7
  const int tc = threadIdx.x & 31;  // 0..31
#pragma unroll
  for (int i = 0; i < 4; ++i) {
    int kk = i * 8 + tr;
    int k = k0 + kk;
    int ksrc = (k < 512) ? (k + 14) : (k - 512);   // permuted source row
    float v = (k < 526) ? W1[(size_t)ksrc * 512 + n0 + tc] : 0.f;
    tile[kk][tc] = v;
  }
  __syncthreads();
#pragma unroll
  for (int i = 0; i < 4; ++i) {
    int nn = i * 8 + tr;
    W1t[(size_t)(n0 + nn) * 544 + k0 + tc] = f2h(tile[tc][nn]);
  }
}

// ---------------- stage 1: LN1 + SELU + concat -> X1 fp16 [B][544] ----------------
__global__ __launch_bounds__(256) void prep_x1(
    const float* __restrict__ feat, const unsigned int* __restrict__ mask,
    const float* __restrict__ jp, const float* __restrict__ jg,
    const float* __restrict__ ln1g, const float* __restrict__ ln1b,
    unsigned short* __restrict__ X1) {
  const int tid = threadIdx.x, wave = tid >> 6, lane = tid & 63;
  const float4* f4 = (const float4*)feat;
  const float4* g4 = (const float4*)ln1g;
  const float4* b4 = (const float4*)ln1b;
#pragma unroll 1
  for (int i = 0; i < 8; ++i) {
    int row = blockIdx.x * 32 + wave * 8 + i;
    float4 a = f4[(size_t)row * 128 + lane * 2];
    float4 b = f4[(size_t)row * 128 + lane * 2 + 1];
    float s = a.x + a.y + a.z + a.w + b.x + b.y + b.z + b.w;
    float q = a.x * a.x + a.y * a.y + a.z * a.z + a.w * a.w +
              b.x * b.x + b.y * b.y + b.z * b.z + b.w * b.w;
#pragma unroll
    for (int d = 32; d > 0; d >>= 1) { s += __shfl_xor(s, d); q += __shfl_xor(q, d); }
    float mk   = mask[row] ? 1.f : 0.f;   // masked-out row => y=0 => selu(ln1_b)
    float mean = mk * s * (1.f / 512.f);
    float msq  = mk * q * (1.f / 512.f);
    float rstd = rsqrtf(msq - mean * mean + 1e-5f);
    float4 g0 = g4[lane * 2], g1 = g4[lane * 2 + 1];
    float4 c0 = b4[lane * 2], c1 = b4[lane * 2 + 1];
    union { unsigned short us[8]; uint4 u; } pk;
    pk.us[0] = f2h(selu_f((a.x * mk - mean) * rstd * g0.x + c0.x));
    pk.us[1] = f2h(selu_f((a.y * mk - mean) * rstd * g0.y + c0.y));
    pk.us[2] = f2h(selu_f((a.z * mk - mean) * rstd * g0.z + c0.z));
    pk.us[3] = f2h(selu_f((a.w * mk - mean) * rstd * g0.w + c0.w));
    pk.us[4] = f2h(selu_f((b.x * mk - mean) * rstd * g1.x + c1.x));
    pk.us[5] = f2h(selu_f((b.y * mk - mean) * rstd * g1.y + c1.y));
    pk.us[6] = f2h(selu_f((b.z * mk - mean) * rstd * g1.z + c1.z));
    pk.us[7] = f2h(selu_f((b.w * mk - mean) * rstd * g1.w + c1.w));
    *(uint4*)&X1[(size_t)row * 544 + lane * 8] = pk.u;
    if (lane < 4) {  // jnt concat tail: cols 512..543 (jp 512..518, jg 519..525, pad 0)
      union { unsigned short us[8]; uint4 u; } tv;
#pragma unroll
      for (int e = 0; e < 8; ++e) {
        int col = 512 + lane * 8 + e;
        float val = 0.f;
        if (col < 519)      val = jp[(size_t)row * 7 + col - 512];
        else if (col < 526) val = jg[(size_t)row * 7 + col - 519];
        tv.us[e] = f2h(val);
      }
      *(uint4*)&X1[(size_t)row * 544 + 512 + lane * 8] = tv.u;
    }
  }
}

// ---------------- stage 2: GEMM1 + LN2 + SELU + GEMM2 + tanh ----------------
struct __align__(16) GSm {
  unsigned short At[64 * 32];   // 4 KB   fp16 A tile (gld16 staged, unpadded)
  unsigned short Bt[512 * 32];  // 32 KB  fp16 B tile (gld16 staged, unpadded)
  float rsum[64], rsq[64], mean2[64], rstd2[64];
  float o[64 * 7];
};

__global__ __launch_bounds__(256) void gemm_main(
    const unsigned short* __restrict__ X1, const unsigned short* __restrict__ W1t,
    const float* __restrict__ b1, const float* __restrict__ ln2g,
    const float* __restrict__ ln2b, const float* __restrict__ W2,
    const float* __restrict__ b2, float* __restrict__ out) {
  __shared__ GSm sm;
  const int tid  = threadIdx.x;
  const int wave = tid >> 6;
  const int lane = tid & 63;
  const int mrow = lane & 15;
  const int quad = lane >> 4;
  const int m0   = blockIdx.x * 64;

  if (tid < 64) {
    sm.rsum[tid] = 0.f; sm.rsq[tid] = 0.f;
#pragma unroll
    for (int j = 0; j < 7; ++j) sm.o[tid * 7 + j] = 0.f;
  }

  f32x4 acc[4][8];
#pragma unroll
  for (int mi = 0; mi < 4; ++mi)
#pragma unroll
    for (int ni = 0; ni < 8; ++ni) acc[mi][ni] = (f32x4){0.f, 0.f, 0.f, 0.f};

  const char* Xb = (const char*)X1 + (size_t)m0 * 1088;

  for (int c = 0; c < KCHUNKS; ++c) {
    if (c) __syncthreads();
    // A tile [64][32] fp16: 1 slot/thread
    gld16(Xb + (size_t)(tid >> 2) * 1088 + c * 64 + (tid & 3) * 16,
          (char*)sm.At + tid * 16);
    // B tile [512][32] fp16: 8 slots/thread
    {
      const char* Wb = (const char*)W1t + c * 64;
#pragma unroll
      for (int i = 0; i < 8; ++i) {
        int s = i * 256 + tid;
        gld16(Wb + (size_t)(s >> 2) * 1088 + (s & 3) * 16, (char*)sm.Bt + s * 16);
      }
    }
    __syncthreads();

    f16x8 aF[4], bF[8];
#pragma unroll
    for (int mi = 0; mi < 4; ++mi)
      aF[mi] = *(const f16x8*)&sm.At[(mi * 16 + mrow) * 32 + quad * 8];
#pragma unroll
    for (int ni = 0; ni < 8; ++ni)
      bF[ni] = *(const f16x8*)&sm.Bt[(wave * 128 + ni * 16 + mrow) * 32 + quad * 8];
#pragma unroll
    for (int mi = 0; mi < 4; ++mi)
#pragma unroll
      for (int ni = 0; ni < 8; ++ni)
        acc[mi][ni] = __builtin_amdgcn_mfma_f32_16x16x32_f16(aF[mi], bF[ni], acc[mi][ni], 0, 0, 0);
  }

  // ---- epilogue: +b1, LN2 stats ----
  float b1v[8], g2v[8], bl2[8];
#pragma unroll
  for (int ni = 0; ni < 8; ++ni) {
    int col = wave * 128 + ni * 16 + mrow;
    b1v[ni] = b1[col]; g2v[ni] = ln2g[col]; bl2[ni] = ln2b[col];
  }
#pragma unroll
  for (int mi = 0; mi < 4; ++mi)
#pragma unroll
    for (int reg = 0; reg < 4; ++reg) {
      int r = mi * 16 + quad * 4 + reg;   // C/D: col=lane&15, row=quad*4+reg
      float s = 0.f, q = 0.f;
#pragma unroll
      for (int ni = 0; ni < 8; ++ni) {
        float v = acc[mi][ni][reg] + b1v[ni];
        acc[mi][ni][reg] = v;
        s += v; q += v * v;
      }
      s += __shfl_xor(s, 1); q += __shfl_xor(q, 1);
      s += __shfl_xor(s, 2); q += __shfl_xor(q, 2);
      s += __shfl_xor(s, 4); q += __shfl_xor(q, 4);
      s += __shfl_xor(s, 8); q += __shfl_xor(q, 8);
      if (mrow == 0) { atomicAdd(&sm.rsum[r], s); atomicAdd(&sm.rsq[r], q); }
    }
  __syncthreads();
  if (tid < 64) {
    float mean = sm.rsum[tid] * (1.f / 512.f);
    float var  = sm.rsq[tid] * (1.f / 512.f) - mean * mean;
    sm.mean2[tid] = mean;
    sm.rstd2[tid] = rsqrtf(var + 1e-5f);
  }
  __syncthreads();

  // ---- LN2 apply + SELU + GEMM2 partials in registers ----
  float w2v[56];
#pragma unroll
  for (int ni = 0; ni < 8; ++ni) {
    int col = wave * 128 + ni * 16 + mrow;
#pragma unroll
    for (int j = 0; j < 7; ++j) w2v[ni * 7 + j] = W2[(size_t)col * 7 + j];
  }
#pragma unroll
  for (int mi = 0; mi < 4; ++mi)
#pragma unroll
    for (int reg = 0; reg < 4; ++reg) {
      int r = mi * 16 + quad * 4 + reg;
      float m2 = sm.mean2[r], rs = sm.rstd2[r];
      float p[7] = {0.f, 0.f, 0.f, 0.f, 0.f, 0.f, 0.f};
#pragma unroll
      for (int ni = 0; ni < 8; ++ni) {
        float v = selu_f((acc[mi][ni][reg] - m2) * rs * g2v[ni] + bl2[ni]);
#pragma unroll
        for (int j = 0; j < 7; ++j) p[j] += v * w2v[ni * 7 + j];
      }
#pragma unroll
      for (int j = 0; j < 7; ++j) {
        p[j] += __shfl_xor(p[j], 1); p[j] += __shfl_xor(p[j], 2);
        p[j] += __shfl_xor(p[j], 4); p[j] += __shfl_xor(p[j], 8);
      }
      if (mrow == 0) {
#pragma unroll
        for (int j = 0; j < 7; ++j) atomicAdd(&sm.o[r * 7 + j], p[j]);
      }
    }
  __syncthreads();
  for (int t = tid; t < 448; t += 256) {
    int r = t / 7, j = t % 7;
    out[(size_t)(m0 + r) * 7 + j] = tanhf(sm.o[r * 7 + j] + b2[j]);
  }
}

// ---------------- fallback (small ws): round-1 fused kernel, known-good ----------------
struct __align__(16) SMemF {
  char buf[35328];
  float mean1[32], rstd1[32], maskf[32];
  float rsum[32], rsq[32], mean2[32], rstd2[32];
};

__global__ __launch_bounds__(256) void actor_fused(
    const float* __restrict__ feat, const unsigned int* __restrict__ mask,
    const float* __restrict__ jp, const float* __restrict__ jg,
    const float* __restrict__ ln1g, const float* __restrict__ ln1b,
    const unsigned short* __restrict__ W1t, const float* __restrict__ b1,
    const float* __restrict__ ln2g, const float* __restrict__ ln2b,
    const float* __restrict__ W2, const float* __restrict__ b2,
    float* __restrict__ out) {
  __shared__ SMemF sm;
  unsigned short* At = (unsigned short*)sm.buf;
  unsigned short* Bt = (unsigned short*)(sm.buf + 2560);
  unsigned short* X2 = (unsigned short*)sm.buf;
  const int tid = threadIdx.x, wave = tid >> 6, lane = tid & 63;
  const int m0 = blockIdx.x * 32, mrow = lane & 15, quad = lane >> 4;
  const float4* f4 = (const float4*)feat;
  for (int i = 0; i < 8; ++i) {
    int lr = wave * 8 + i, row = m0 + lr;
    float4 a = f4[(size_t)row * 128 + lane * 2];
    float4 b = f4[(size_t)row * 128 + lane * 2 + 1];
    float s = a.x + a.y + a.z + a.w + b.x + b.y + b.z + b.w;
    float q = a.x * a.x + a.y * a.y + a.z * a.z + a.w * a.w +
              b.x * b.x + b.y * b.y + b.z * b.z + b.w * b.w;
#pragma unroll
    for (int d = 32; d > 0; d >>= 1) { s += __shfl_xor(s, d); q += __shfl_xor(q, d); }
    if (lane == 0) {
      float mk = mask[row] ? 1.f : 0.f;
      float mean = mk * s * (1.f / 512.f), msq = mk * q * (1.f / 512.f);
      sm.mean1[lr] = mean; sm.rstd1[lr] = rsqrtf(msq - mean * mean + 1e-5f);
      sm.maskf[lr] = mk;
    }
  }
  if (tid < 32) { sm.rsum[tid] = 0.f; sm.rsq[tid] = 0.f; }
  __syncthreads();
  f32x4 acc[2][8];
#pragma unroll
  for (int mi = 0; mi < 2; ++mi)
#pragma unroll
    for (int ni = 0; ni < 8; ++ni) acc[mi][ni] = (f32x4){0.f, 0.f, 0.f, 0.f};
  const int arow = tid >> 3, acg = tid & 7;
  for (int c = 0; c < KCHUNKS; ++c) {
    if (c) __syncthreads();
    float v0, v1, v2, v3;
    if (c < 16) {
      float4 f = f4[(size_t)(m0 + arow) * 128 + c * 8 + acg];
      float mk = sm.maskf[arow], mean = sm.mean1[arow], rstd = sm.rstd1[arow];
      float4 g = ((const float4*)ln1g)[c * 8 + acg];
      float4 b = ((const float4*)ln1b)[c * 8 + acg];
      v0 = selu_f((f.x * mk - mean) * rstd * g.x + b.x);
      v1 = selu_f((f.y * mk - mean) * rstd * g.y + b.y);
      v2 = selu_f((f.z * mk - mean) * rstd * g.z + b.z);
      v3 = selu_f((f.w * mk - mean) * rstd * g.w + b.w);
    } else {
      int row = m0 + arow; float t[4];
#pragma unroll
      for (int q2 = 0; q2 < 4; ++q2) {
        int kk = acg * 4 + q2; float val = 0.f;
        if (kk < 7) val = jp[(size_t)row * 7 + kk];
        else if (kk < 14) val = jg[(size_t)row * 7 + kk - 7];
        t[q2] = val;
      }
      v0 = t[0]; v1 = t[1]; v2 = t[2]; v3 = t[3];
    }
    { union { unsigned short us[4]; uint2 u; } pk;
      pk.us[0] = f2h(v0); pk.us[1] = f2h(v1); pk.us[2] = f2h(v2); pk.us[3] = f2h(v3);
      *(uint2*)&At[arow * 40 + acg * 4] = pk.u; }
    { const char* wb = (const char*)W1t + (size_t)c * 64;
      char* lb = (char*)Bt + (size_t)(wave * 64) * 16;
#pragma unroll
      for (int i = 0; i < 8; ++i) {
        int slot = i * 256 + tid;
        gld16(wb + (size_t)(slot >> 2) * 1088 + (size_t)(slot & 3) * 16,
              lb + (size_t)i * 4096);
      } }
    __syncthreads();
    f16x8 aF[2], bF[8];
#pragma unroll
    for (int mi = 0; mi < 2; ++mi)
      aF[mi] = *(const f16x8*)&At[(mi * 16 + mrow) * 40 + quad * 8];
#pragma unroll
    for (int ni = 0; ni < 8; ++ni)
      bF[ni] = *(const f16x8*)&Bt[(wave * 128 + ni * 16 + mrow) * 32 + quad * 8];
#pragma unroll
    for (int mi = 0; mi < 2; ++mi)
#pragma unroll
      for (int ni = 0; ni < 8; ++ni)
        acc[mi][ni] = __builtin_amdgcn_mfma_f32_16x16x32_f16(aF[mi], bF[ni], acc[mi][ni], 0, 0, 0);
  }
  float b1v[8], g2v[8], bl2v[8];
#pragma unroll
  for (int ni = 0; ni < 8; ++ni) {
    int col = wave * 128 + ni * 16 + mrow;
    b1v[ni] = b1[col]; g2v[ni] = ln2g[col]; bl2v[ni] = ln2b[col];
  }
#pragma unroll
  for (int mi = 0; mi < 2; ++mi)
#pragma unroll
    for (int reg = 0; reg < 4; ++reg) {
      int r = mi * 16 + quad * 4 + reg;
      float s = 0.f, q = 0.f;
#pragma unroll
      for (int ni = 0; ni < 8; ++ni) {
        float v = acc[mi][ni][reg] + b1v[ni];
        acc[mi][ni][reg] = v; s += v; q += v * v;
      }
      s += __shfl_xor(s, 1); q += __shfl_xor(q, 1);
      s += __shfl_xor(s, 2); q += __shfl_xor(q, 2);
      s += __shfl_xor(s, 4); q += __shfl_xor(q, 4);
      s += __shfl_xor(s, 8); q += __shfl_xor(q, 8);
      if ((lane & 15) == 0) { atomicAdd(&sm.rsum[r], s); atomicAdd(&sm.rsq[r], q); }
    }
  __syncthreads();
  if (tid < 32) {
    float mean = sm.rsum[tid] * (1.f / 512.f);
    float var = sm.rsq[tid] * (1.f / 512.f) - mean * mean;
    sm.mean2[tid] = mean; sm.rstd2[tid] = rsqrtf(var + 1e-5f);
  }
  __syncthreads();
#pragma unroll
  for (int mi = 0; mi < 2; ++mi)
#pragma unroll
    for (int ni = 0; ni < 8; ++ni)
#pragma unroll
      for (int reg = 0; reg < 4; ++reg) {
        int r = mi * 16 + quad * 4 + reg;
        int col = wave * 128 + ni * 16 + mrow;
        float v = (acc[mi][ni][reg] - sm.mean2[r]) * sm.rstd2[r] * g2v[ni] + bl2v[ni];
        X2[r * 520 + col] = f2h(selu_f(v));
      }
  __syncthreads();
  float w2r[56];
  { const float4* wp = (const float4*)W2 + lane * 14;
#pragma unroll
    for (int i = 0; i < 14; ++i) {
      float4 t = wp[i];
      w2r[i * 4 + 0] = t.x; w2r[i * 4 + 1] = t.y;
      w2r[i * 4 + 2] = t.z; w2r[i * 4 + 3] = t.w;
    } }
  float b2v = (lane < 7) ? b2[lane] : 0.f;
  for (int i = 0; i < 8; ++i) {
    int r = wave * 8 + i;
    f16x8 xv = *(const f16x8*)&X2[r * 520 + lane * 8];
    float o0 = 0, o1 = 0, o2 = 0, o3 = 0, o4 = 0, o5 = 0, o6 = 0;
#pragma unroll
    for (int e = 0; e < 8; ++e) {
      float xf = (float)xv[e];
      o0 += xf * w2r[e * 7 + 0]; o1 += xf * w2r[e * 7 + 1];
      o2 += xf * w2r[e * 7 + 2]; o3 += xf * w2r[e * 7 + 3];
      o4 += xf * w2r[e * 7 + 4]; o5 += xf * w2r[e * 7 + 5];
      o6 += xf * w2r[e * 7 + 6];
    }
#pragma unroll
    for (int d = 32; d > 0; d >>= 1) {
      o0 += __shfl_xor(o0, d); o1 += __shfl_xor(o1, d); o2 += __shfl_xor(o2, d);
      o3 += __shfl_xor(o3, d); o4 += __shfl_xor(o4, d); o5 += __shfl_xor(o5, d);
      o6 += __shfl_xor(o6, d);
    }
    if (lane < 7) {
      float ov = o0;
      if (lane == 1) ov = o1; else if (lane == 2) ov = o2;
      else if (lane == 3) ov = o3; else if (lane == 4) ov = o4;
      else if (lane == 5) ov = o5; else if (lane == 6) ov = o6;
      out[(size_t)(m0 + r) * 7 + lane] = tanhf(ov + b2v);
    }
  }
}

extern "C" void kernel_launch(void* const* d_in, const int* in_sizes, int n_in,
                              void* d_out, int out_size, void* d_ws, size_t ws_size,
                              hipStream_t stream) {
  const float* feat = (const float*)d_in[0];
  const int*   crd  = (const int*)d_in[1];
  const float* jp   = (const float*)d_in[2];
  const float* jg   = (const float*)d_in[3];
  const float* ln1g = (const float*)d_in[4];
  const float* ln1b = (const float*)d_in[5];
  const float* W1   = (const float*)d_in[6];
  const float* b1   = (const float*)d_in[7];
  const float* ln2g = (const float*)d_in[8];
  const float* ln2b = (const float*)d_in[9];
  const float* W2   = (const float*)d_in[10];
  const float* b2   = (const float*)d_in[11];
  float* out = (float*)d_out;

  unsigned int*   mask = (unsigned int*)d_ws;
  unsigned short* W1t  = (unsigned short*)((char*)d_ws + W1T_OFF);
  unsigned short* X1   = (unsigned short*)((char*)d_ws + X1_OFF);

  hipMemsetAsync(mask, 0, (size_t)B_ROWS * 4, stream);
  scatter_mask<<<B_ROWS / 256, 256, 0, stream>>>(crd, mask);
  build_w1t<<<dim3(17, 16), 256, 0, stream>>>(W1, W1t);

  if (ws_size >= WS_NEED) {
    prep_x1<<<B_ROWS / 32, 256, 0, stream>>>(feat, mask, jp, jg, ln1g, ln1b, X1);
    gemm_main<<<B_ROWS / 64, 256, 0, stream>>>(X1, W1t, b1, ln2g, ln2b, W2, b2, out);
  } else {
    actor_fused<<<B_ROWS / 32, 256, 0, stream>>>(
        feat, mask, jp, jg, ln1g, ln1b, W1t, b1, ln2g, ln2b, W2, b2, out);
  }
}